// Round 1
// baseline (457.634 us; speedup 1.0000x reference)
//
#include <hip/hip_runtime.h>

#define WAVE 64
#define NXCD 8
#define NRMAX 200
#define RSTRIDE 17      // float4 units: 272B row stride -> per-rel start-bank offset 4*(rel%8)
#define HOP_TPB 1024
#define HOP_BLOCKS 512

// rT layout: [layer][N_R][64]  (batch innermost, matches lane)
__global__ void compute_r_kernel(const float* __restrict__ q,
                                 const float* __restrict__ W1, const float* __restrict__ b1,
                                 const float* __restrict__ W2, const float* __restrict__ b2,
                                 const float* __restrict__ W3, const float* __restrict__ b3,
                                 float* __restrict__ rT, int N_R, int N_W2V) {
    int lane = threadIdx.x & 63;
    int wv   = threadIdx.x >> 6;
    int b    = blockIdx.y * 4 + wv;
    int it   = blockIdx.x * 64 + lane;
    if (it >= 3 * N_R) return;
    int l = it / N_R;
    int j = it - l * N_R;
    const float* W  = (l == 0) ? W1 : (l == 1) ? W2 : W3;
    const float* bv = (l == 0) ? b1 : (l == 1) ? b2 : b3;
    const float* qrow = q + (size_t)b * N_W2V;
    float a0 = 0.f, a1 = 0.f, a2 = 0.f, a3 = 0.f;
    int k = 0;
    for (; k + 4 <= N_W2V; k += 4) {
        a0 = fmaf(qrow[k + 0], W[(size_t)(k + 0) * N_R + j], a0);
        a1 = fmaf(qrow[k + 1], W[(size_t)(k + 1) * N_R + j], a1);
        a2 = fmaf(qrow[k + 2], W[(size_t)(k + 2) * N_R + j], a2);
        a3 = fmaf(qrow[k + 3], W[(size_t)(k + 3) * N_R + j], a3);
    }
    for (; k < N_W2V; ++k)
        a0 = fmaf(qrow[k], W[(size_t)k * N_R + j], a0);
    rT[(size_t)it * WAVE + b] = bv[j] + ((a0 + a1) + (a2 + a3));
}

// x (B=64, N_E) -> xT (N_E, 64)
__global__ void transpose_in_kernel(const float* __restrict__ in, float* __restrict__ out, int N_E) {
    __shared__ float tile[64][65];
    int e0 = blockIdx.x * 64;
    int li = threadIdx.x & 63;
    int lo = threadIdx.x >> 6;
    #pragma unroll
    for (int k = 0; k < 16; ++k) {
        int b = lo + 4 * k;
        int e = e0 + li;
        tile[b][li] = (e < N_E) ? in[(size_t)b * N_E + e] : 0.0f;
    }
    __syncthreads();
    #pragma unroll
    for (int k = 0; k < 16; ++k) {
        int i = lo + 4 * k;
        int e = e0 + i;
        if (e < N_E) out[(size_t)e * 64 + li] = tile[li][i];
    }
}

// ---- CSR build ----
// R5 lesson: un-sharded random 4B scatter writes cost 17x HBM write
// amplification (64B lines dirtied in multiple non-coherent XCD L2s).
// Group g = blockIdx%8 owns entity range; only touches its own slice.

__global__ void count_kernel(const int* __restrict__ obj, int* __restrict__ counts,
                             int nT, int nE) {
    int grp = blockIdx.x & (NXCD - 1);
    int sh  = (nE + NXCD - 1) / NXCD;
    int lo  = grp * sh;
    int hi  = min(nE, lo + sh);
    int tid    = (blockIdx.x >> 3) * blockDim.x + threadIdx.x;
    int stride = (gridDim.x >> 3) * blockDim.x;
    for (int t = tid; t < nT; t += stride) {
        int o = obj[t];
        if (o >= lo && o < hi) atomicAdd(&counts[o], 1);
    }
}

__global__ void scanA_kernel(const int* __restrict__ counts, int* __restrict__ partials, int nE) {
    __shared__ int lds[256];
    int i = blockIdx.x * 256 + threadIdx.x;
    lds[threadIdx.x] = (i < nE) ? counts[i] : 0;
    __syncthreads();
    for (int off = 128; off > 0; off >>= 1) {
        if (threadIdx.x < off) lds[threadIdx.x] += lds[threadIdx.x + off];
        __syncthreads();
    }
    if (threadIdx.x == 0) partials[blockIdx.x] = lds[0];
}

// single block, nP <= 1024 (here nP = ceil(200000/256) = 782)
__global__ void scanB_kernel(int* __restrict__ partials, int nP) {
    __shared__ int lds[1024];
    int tid = threadIdx.x;
    lds[tid] = (tid < nP) ? partials[tid] : 0;
    __syncthreads();
    for (int off = 1; off < 1024; off <<= 1) {
        int v = (tid >= off) ? lds[tid - off] : 0;
        __syncthreads();
        lds[tid] += v;
        __syncthreads();
    }
    if (tid < nP) partials[tid] = (tid == 0) ? 0 : lds[tid - 1];
}

__global__ void scanC_kernel(const int* __restrict__ counts, const int* __restrict__ partials,
                             int* __restrict__ row_ptr, int* __restrict__ cursor, int nE) {
    __shared__ int lds[256];
    int i = blockIdx.x * 256 + threadIdx.x;
    int c = (i < nE) ? counts[i] : 0;
    lds[threadIdx.x] = c;
    __syncthreads();
    for (int off = 1; off < 256; off <<= 1) {
        int v = (threadIdx.x >= off) ? lds[threadIdx.x - off] : 0;
        __syncthreads();
        lds[threadIdx.x] += v;
        __syncthreads();
    }
    int excl = partials[blockIdx.x] + ((threadIdx.x == 0) ? 0 : lds[threadIdx.x - 1]);
    if (i < nE) { row_ptr[i] = excl; cursor[i] = excl; }
    if (i == nE - 1) row_ptr[nE] = excl + c;
}

// packed = subj | (rel<<18). Valid for N_E < 2^18, N_R < 2^14 (here 200000/200).
__global__ void scatter_kernel(const int* __restrict__ subj, const int* __restrict__ rel,
                               const int* __restrict__ obj, int* __restrict__ cursor,
                               unsigned* __restrict__ packed, int nT, int nE) {
    int grp = blockIdx.x & (NXCD - 1);
    int sh  = (nE + NXCD - 1) / NXCD;
    int lo  = grp * sh;
    int hi  = min(nE, lo + sh);
    int tid    = (blockIdx.x >> 3) * blockDim.x + threadIdx.x;
    int stride = (gridDim.x >> 3) * blockDim.x;
    for (int t = tid; t < nT; t += stride) {
        int o = obj[t];
        if (o >= lo && o < hi) {
            int slot = atomicAdd(&cursor[o], 1);
            packed[slot] = (unsigned)subj[t] | ((unsigned)rel[t] << 18);
        }
    }
}

// R9: r gathers moved off the vmem path into LDS (whole layer = 51KB,
// was L2-resident anyway; per-triple 256B r-row gather wasted half the
// L1/TA request budget). Row stride RSTRIDE=17 float4 (272B) so rel rows
// start at bank 4*(rel%8) instead of all at bank 0 (8-way conflict).
// x gathers stay on vmem: plain b128 loads, 16 lanes x 16B per entity row.
__device__ __forceinline__ float4 hop_accum4(const float4* __restrict__ xT4,
                                             const float4* __restrict__ r_lds,
                                             const int* __restrict__ row_ptr,
                                             const unsigned* __restrict__ packed,
                                             int e, int g, int c, int nE) {
    float4 acc = make_float4(0.f, 0.f, 0.f, 0.f);
    bool ev = e < nE;
    int beg = ev ? row_ptr[e] : 0;
    int end = ev ? row_ptr[e + 1] : 0;
    int len = end - beg;
    unsigned pv = (c < len) ? packed[beg + c] : 0u;   // stage first 16 idx of this group's bucket
    int n16 = min(len, 16);
    int m = max(n16, __shfl_xor(n16, 16));            // wave-max over the 4 groups
    m = max(m, __shfl_xor(m, 32));
    for (int j0 = 0; j0 < m; j0 += 4) {
        float4 xv[4], rv[4];
        #pragma unroll
        for (int u = 0; u < 4; ++u) {
            int jj = max(min(j0 + u, len - 1), 0);    // clamp: dup loads hit hot lines
            unsigned p = __shfl(pv, (g << 4) + jj);   // per-lane src index: group-local broadcast
            xv[u] = xT4[(size_t)(p & 0x3FFFFu) * 16 + c];
            rv[u] = r_lds[(p >> 18) * RSTRIDE + c];
        }
        #pragma unroll
        for (int u = 0; u < 4; ++u) {
            if (j0 + u < len) {
                acc.x = fmaf(xv[u].x, rv[u].x, acc.x);
                acc.y = fmaf(xv[u].y, rv[u].y, acc.y);
                acc.z = fmaf(xv[u].z, rv[u].z, acc.z);
                acc.w = fmaf(xv[u].w, rv[u].w, acc.w);
            }
        }
    }
    // rare overflow (len > 16): per-group sequential, wave votes to exit
    int j = 16;
    while (__any(j < len)) {
        if (j < len) {
            unsigned p = packed[beg + j];
            float4 xv = xT4[(size_t)(p & 0x3FFFFu) * 16 + c];
            float4 rv = r_lds[(p >> 18) * RSTRIDE + c];
            acc.x = fmaf(xv.x, rv.x, acc.x);
            acc.y = fmaf(xv.y, rv.y, acc.y);
            acc.z = fmaf(xv.z, rv.z, acc.z);
            acc.w = fmaf(xv.w, rv.w, acc.w);
        }
        ++j;
    }
    return acc;
}

// hops 1-2: 1024-thread blocks (16 waves x 4 entities = 64-entity tiles),
// grid-stride over tiles with 512 resident blocks (2/CU, 32 waves/CU = 100%
// occupancy; LDS 54.4KB/block). r staged once per block: 512*51KB = 26MB.
__global__ __launch_bounds__(HOP_TPB, 8)
void hop_csr_kernel(const float4* __restrict__ xT4, const float4* __restrict__ rT4,
                    const int* __restrict__ row_ptr, const unsigned* __restrict__ packed,
                    float4* __restrict__ yT4, int nE, int nR) {
    __shared__ float4 r_lds[NRMAX * RSTRIDE];
    for (int i = threadIdx.x; i < nR * 16; i += HOP_TPB)
        r_lds[(i >> 4) * RSTRIDE + (i & 15)] = rT4[i];
    __syncthreads();
    int lane = threadIdx.x & 63;
    int g = lane >> 4, c = lane & 15;
    int wv = threadIdx.x >> 6;                   // 0..15
    int nTiles = (nE + 63) >> 6;
    for (int t = blockIdx.x; t < nTiles; t += gridDim.x) {
        int e = t * 64 + wv * 4 + g;
        float4 acc = hop_accum4(xT4, r_lds, row_ptr, packed, e, g, c, nE);
        if (e < nE) yT4[(size_t)e * 16 + c] = acc;
    }
}

// hop 3 fused with output transpose: 64-entity LDS tile, stores (B, N_E).
// LDS: 54.4KB r + 16.6KB tile = 71KB -> still 2 blocks/CU (142KB <= 160KB).
__global__ __launch_bounds__(HOP_TPB, 8)
void hop_csr_out_kernel(const float4* __restrict__ xT4, const float4* __restrict__ rT4,
                        const int* __restrict__ row_ptr, const unsigned* __restrict__ packed,
                        float* __restrict__ out, int nE, int nR) {
    __shared__ float4 r_lds[NRMAX * RSTRIDE];
    __shared__ float tile[64][65];
    for (int i = threadIdx.x; i < nR * 16; i += HOP_TPB)
        r_lds[(i >> 4) * RSTRIDE + (i & 15)] = rT4[i];
    __syncthreads();
    int lane = threadIdx.x & 63;
    int g = lane >> 4, c = lane & 15;
    int wv = threadIdx.x >> 6;                   // 0..15
    int nTiles = (nE + 63) >> 6;
    for (int t = blockIdx.x; t < nTiles; t += gridDim.x) {
        int e0 = t * 64;
        int ei = wv * 4 + g;                     // 0..63 unique per (wv,g)
        float4 acc = hop_accum4(xT4, r_lds, row_ptr, packed, e0 + ei, g, c, nE);
        tile[ei][4 * c + 0] = acc.x;
        tile[ei][4 * c + 1] = acc.y;
        tile[ei][4 * c + 2] = acc.z;
        tile[ei][4 * c + 3] = acc.w;
        __syncthreads();
        #pragma unroll
        for (int k = 0; k < 4; ++k) {
            int b = wv * 4 + k;
            int e = e0 + lane;
            if (e < nE) out[(size_t)b * nE + e] = tile[lane][b];
        }
        __syncthreads();                         // tile reused next iteration
    }
}

extern "C" void kernel_launch(void* const* d_in, const int* in_sizes, int n_in,
                              void* d_out, int out_size, void* d_ws, size_t ws_size,
                              hipStream_t stream) {
    const float* x  = (const float*)d_in[0];
    const float* q  = (const float*)d_in[1];
    const float* W1 = (const float*)d_in[2];
    const float* b1 = (const float*)d_in[3];
    const float* W2 = (const float*)d_in[4];
    const float* b2 = (const float*)d_in[5];
    const float* W3 = (const float*)d_in[6];
    const float* b3 = (const float*)d_in[7];
    const int* subj = (const int*)d_in[8];
    const int* rel  = (const int*)d_in[9];
    const int* obj  = (const int*)d_in[10];
    // n_hop (d_in[11]) is the constant 3 per the reference; hops hardcoded.

    const int B     = 64;
    const int N_E   = in_sizes[0] / B;   // 200000
    const int N_W2V = in_sizes[1] / B;   // 300
    const int N_R   = in_sizes[3];       // 200
    const int N_T   = in_sizes[8];       // 1000000

    const size_t xelems = (size_t)N_E * B;
    const size_t xbytes = xelems * sizeof(float);

    // ws layout: [counts nE][row_ptr nE+4 (pad keeps rT 16B-aligned)][cursor nE]
    //            [packed nT][rT 3*N_R*64][bufA][bufB?]
    int*      counts  = (int*)d_ws;
    int*      row_ptr = counts + N_E;
    int*      cursor  = row_ptr + (N_E + 4);
    unsigned* packed  = (unsigned*)(cursor + N_E);
    float*    rT      = (float*)(packed + N_T);          // 16B-aligned by construction
    float*    bufA    = rT + (size_t)3 * N_R * B;
    size_t used = (size_t)((char*)bufA - (char*)d_ws) + xbytes;

    float* bufB;
    if (ws_size >= used + xbytes) {
        bufB = bufA + xelems;
    } else {
        bufB = (float*)d_out;   // mid-run scratch; final write is hop_csr_out
    }

    // scan partials: steal tail of ws if free, else tail of packed (safe:
    // packed written only after scanC consumed partials).
    int nScan = (N_E + 255) / 256;       // 782
    int* partials = (int*)((char*)d_ws + ws_size - 4096);
    if ((size_t)((char*)partials - (char*)d_ws) < used + ((bufB == (float*)d_out) ? 0 : xbytes))
        partials = (int*)packed + (N_T - 1024);

    // 1) r for all three layers
    {
        dim3 rgrid((3 * N_R + 63) / 64, B / 4);
        compute_r_kernel<<<rgrid, 256, 0, stream>>>(q, W1, b1, W2, b2, W3, b3, rT, N_R, N_W2V);
    }

    // 2) transpose x -> bufA
    int tgrid = (N_E + 63) / 64;
    transpose_in_kernel<<<tgrid, 256, 0, stream>>>(x, bufA, N_E);

    // 3) CSR build (XCD-sharded count -> scan -> XCD-sharded scatter)
    hipMemsetAsync(counts, 0, (size_t)N_E * sizeof(int), stream);
    count_kernel<<<1024, 256, 0, stream>>>(obj, counts, N_T, N_E);
    scanA_kernel<<<nScan, 256, 0, stream>>>(counts, partials, N_E);
    scanB_kernel<<<1, 1024, 0, stream>>>(partials, nScan);
    scanC_kernel<<<nScan, 256, 0, stream>>>(counts, partials, row_ptr, cursor, N_E);
    scatter_kernel<<<1024, 256, 0, stream>>>(subj, rel, obj, cursor, packed, N_T, N_E);

    // 4) three hops; hop3 fuses the output transpose
    int nTiles  = (N_E + 63) / 64;                 // 3125
    int hblocks = nTiles < HOP_BLOCKS ? nTiles : HOP_BLOCKS;
    hop_csr_kernel<<<hblocks, HOP_TPB, 0, stream>>>((const float4*)bufA, (const float4*)rT,
                                                    row_ptr, packed, (float4*)bufB, N_E, N_R);
    hop_csr_kernel<<<hblocks, HOP_TPB, 0, stream>>>((const float4*)bufB, (const float4*)(rT + (size_t)1 * N_R * B),
                                                    row_ptr, packed, (float4*)bufA, N_E, N_R);
    hop_csr_out_kernel<<<hblocks, HOP_TPB, 0, stream>>>((const float4*)bufA, (const float4*)(rT + (size_t)2 * N_R * B),
                                                        row_ptr, packed, (float*)d_out, N_E, N_R);
}

// Round 2
// 388.538 us; speedup vs baseline: 1.1778x; 1.1778x over previous
//
#include <hip/hip_runtime.h>
#include <hip/hip_fp16.h>

#define WAVE 64
#define NXCD 8
#define NRMAX 200
#define RSTRIDE 17      // float4 units: 272B row stride -> per-rel start-bank offset 4*(rel%8)
#define HOP_TPB 1024
#define HOP_BLOCKS 512

// rT layout: [layer][N_R][64]  (batch innermost, matches lane)
__global__ void compute_r_kernel(const float* __restrict__ q,
                                 const float* __restrict__ W1, const float* __restrict__ b1,
                                 const float* __restrict__ W2, const float* __restrict__ b2,
                                 const float* __restrict__ W3, const float* __restrict__ b3,
                                 float* __restrict__ rT, int N_R, int N_W2V) {
    int lane = threadIdx.x & 63;
    int wv   = threadIdx.x >> 6;
    int b    = blockIdx.y * 4 + wv;
    int it   = blockIdx.x * 64 + lane;
    if (it >= 3 * N_R) return;
    int l = it / N_R;
    int j = it - l * N_R;
    const float* W  = (l == 0) ? W1 : (l == 1) ? W2 : W3;
    const float* bv = (l == 0) ? b1 : (l == 1) ? b2 : b3;
    const float* qrow = q + (size_t)b * N_W2V;
    float a0 = 0.f, a1 = 0.f, a2 = 0.f, a3 = 0.f;
    int k = 0;
    for (; k + 4 <= N_W2V; k += 4) {
        a0 = fmaf(qrow[k + 0], W[(size_t)(k + 0) * N_R + j], a0);
        a1 = fmaf(qrow[k + 1], W[(size_t)(k + 1) * N_R + j], a1);
        a2 = fmaf(qrow[k + 2], W[(size_t)(k + 2) * N_R + j], a2);
        a3 = fmaf(qrow[k + 3], W[(size_t)(k + 3) * N_R + j], a3);
    }
    for (; k < N_W2V; ++k)
        a0 = fmaf(qrow[k], W[(size_t)k * N_R + j], a0);
    rT[(size_t)it * WAVE + b] = bv[j] + ((a0 + a1) + (a2 + a3));
}

// x (B=64, N_E) -> xT (N_E, 64)
__global__ void transpose_in_kernel(const float* __restrict__ in, float* __restrict__ out, int N_E) {
    __shared__ float tile[64][65];
    int e0 = blockIdx.x * 64;
    int li = threadIdx.x & 63;
    int lo = threadIdx.x >> 6;
    #pragma unroll
    for (int k = 0; k < 16; ++k) {
        int b = lo + 4 * k;
        int e = e0 + li;
        tile[b][li] = (e < N_E) ? in[(size_t)b * N_E + e] : 0.0f;
    }
    __syncthreads();
    #pragma unroll
    for (int k = 0; k < 16; ++k) {
        int i = lo + 4 * k;
        int e = e0 + i;
        if (e < N_E) out[(size_t)e * 64 + li] = tile[li][i];
    }
}

// ---- CSR build ----
// R5 lesson: un-sharded random 4B scatter writes cost 17x HBM write
// amplification (64B lines dirtied in multiple non-coherent XCD L2s).
// Group g = blockIdx%8 owns entity range; only touches its own slice.

__global__ void count_kernel(const int* __restrict__ obj, int* __restrict__ counts,
                             int nT, int nE) {
    int grp = blockIdx.x & (NXCD - 1);
    int sh  = (nE + NXCD - 1) / NXCD;
    int lo  = grp * sh;
    int hi  = min(nE, lo + sh);
    int tid    = (blockIdx.x >> 3) * blockDim.x + threadIdx.x;
    int stride = (gridDim.x >> 3) * blockDim.x;
    for (int t = tid; t < nT; t += stride) {
        int o = obj[t];
        if (o >= lo && o < hi) atomicAdd(&counts[o], 1);
    }
}

__global__ void scanA_kernel(const int* __restrict__ counts, int* __restrict__ partials, int nE) {
    __shared__ int lds[256];
    int i = blockIdx.x * 256 + threadIdx.x;
    lds[threadIdx.x] = (i < nE) ? counts[i] : 0;
    __syncthreads();
    for (int off = 128; off > 0; off >>= 1) {
        if (threadIdx.x < off) lds[threadIdx.x] += lds[threadIdx.x + off];
        __syncthreads();
    }
    if (threadIdx.x == 0) partials[blockIdx.x] = lds[0];
}

// single block, nP <= 1024 (here nP = ceil(200000/256) = 782)
__global__ void scanB_kernel(int* __restrict__ partials, int nP) {
    __shared__ int lds[1024];
    int tid = threadIdx.x;
    lds[tid] = (tid < nP) ? partials[tid] : 0;
    __syncthreads();
    for (int off = 1; off < 1024; off <<= 1) {
        int v = (tid >= off) ? lds[tid - off] : 0;
        __syncthreads();
        lds[tid] += v;
        __syncthreads();
    }
    if (tid < nP) partials[tid] = (tid == 0) ? 0 : lds[tid - 1];
}

__global__ void scanC_kernel(const int* __restrict__ counts, const int* __restrict__ partials,
                             int* __restrict__ row_ptr, int* __restrict__ cursor, int nE) {
    __shared__ int lds[256];
    int i = blockIdx.x * 256 + threadIdx.x;
    int c = (i < nE) ? counts[i] : 0;
    lds[threadIdx.x] = c;
    __syncthreads();
    for (int off = 1; off < 256; off <<= 1) {
        int v = (threadIdx.x >= off) ? lds[threadIdx.x - off] : 0;
        __syncthreads();
        lds[threadIdx.x] += v;
        __syncthreads();
    }
    int excl = partials[blockIdx.x] + ((threadIdx.x == 0) ? 0 : lds[threadIdx.x - 1]);
    if (i < nE) { row_ptr[i] = excl; cursor[i] = excl; }
    if (i == nE - 1) row_ptr[nE] = excl + c;
}

// packed = subj | (rel<<18). Valid for N_E < 2^18, N_R < 2^14 (here 200000/200).
__global__ void scatter_kernel(const int* __restrict__ subj, const int* __restrict__ rel,
                               const int* __restrict__ obj, int* __restrict__ cursor,
                               unsigned* __restrict__ packed, int nT, int nE) {
    int grp = blockIdx.x & (NXCD - 1);
    int sh  = (nE + NXCD - 1) / NXCD;
    int lo  = grp * sh;
    int hi  = min(nE, lo + sh);
    int tid    = (blockIdx.x >> 3) * blockDim.x + threadIdx.x;
    int stride = (gridDim.x >> 3) * blockDim.x;
    for (int t = tid; t < nT; t += stride) {
        int o = obj[t];
        if (o >= lo && o < hi) {
            int slot = atomicAdd(&cursor[o], 1);
            packed[slot] = (unsigned)subj[t] | ((unsigned)rel[t] << 18);
        }
    }
}

// R10: R9's null result (rT->LDS, dur/FETCH unchanged) proved the hop is
// past-L2-byte-bound, not request-bound. So: halve the bytes. Intermediates
// x1,x2 stored fp16 (values O(1), fp32 accumulation; only 2 roundings).
// Gather row 256B->128B, footprint 51.2->25.6MB (L2 hit rate also rises),
// intermediate writes halved. Wave shape unchanged: 4 entities x 16 lanes,
// lane c covers batch cols 4c..4c+3 (dwordx2 instead of dwordx4).

struct F32Row {       // row = 16 x float4 (256B)
    const float4* p;
    __device__ __forceinline__ float4 load(unsigned e, int c) const {
        return p[(size_t)e * 16 + c];
    }
};
struct F16Row {       // row = 16 x uint2 (128B, 4 halves per lane)
    const uint2* p;
    __device__ __forceinline__ float4 load(unsigned e, int c) const {
        uint2 v = p[(size_t)e * 16 + c];
        __half2 h0 = *(__half2*)&v.x;
        __half2 h1 = *(__half2*)&v.y;
        float2 f0 = __half22float2(h0);
        float2 f1 = __half22float2(h1);
        return make_float4(f0.x, f0.y, f1.x, f1.y);
    }
};

__device__ __forceinline__ uint2 pack_half4(float4 a) {
    __half2 h0 = __floats2half2_rn(a.x, a.y);
    __half2 h1 = __floats2half2_rn(a.z, a.w);
    uint2 v;
    v.x = *(unsigned*)&h0;
    v.y = *(unsigned*)&h1;
    return v;
}

template<typename XS>
__device__ __forceinline__ float4 hop_accum4(XS xs,
                                             const float4* __restrict__ r_lds,
                                             const int* __restrict__ row_ptr,
                                             const unsigned* __restrict__ packed,
                                             int e, int g, int c, int nE) {
    float4 acc = make_float4(0.f, 0.f, 0.f, 0.f);
    bool ev = e < nE;
    int beg = ev ? row_ptr[e] : 0;
    int end = ev ? row_ptr[e + 1] : 0;
    int len = end - beg;
    unsigned pv = (c < len) ? packed[beg + c] : 0u;   // stage first 16 idx of this group's bucket
    int n16 = min(len, 16);
    int m = max(n16, __shfl_xor(n16, 16));            // wave-max over the 4 groups
    m = max(m, __shfl_xor(m, 32));
    for (int j0 = 0; j0 < m; j0 += 4) {
        float4 xv[4], rv[4];
        #pragma unroll
        for (int u = 0; u < 4; ++u) {
            int jj = max(min(j0 + u, len - 1), 0);    // clamp: dup loads hit hot lines
            unsigned p = __shfl(pv, (g << 4) + jj);   // per-lane src index: group-local broadcast
            xv[u] = xs.load(p & 0x3FFFFu, c);
            rv[u] = r_lds[(p >> 18) * RSTRIDE + c];
        }
        #pragma unroll
        for (int u = 0; u < 4; ++u) {
            if (j0 + u < len) {
                acc.x = fmaf(xv[u].x, rv[u].x, acc.x);
                acc.y = fmaf(xv[u].y, rv[u].y, acc.y);
                acc.z = fmaf(xv[u].z, rv[u].z, acc.z);
                acc.w = fmaf(xv[u].w, rv[u].w, acc.w);
            }
        }
    }
    // rare overflow (len > 16): per-group sequential, wave votes to exit
    int j = 16;
    while (__any(j < len)) {
        if (j < len) {
            unsigned p = packed[beg + j];
            float4 xv = xs.load(p & 0x3FFFFu, c);
            float4 rv = r_lds[(p >> 18) * RSTRIDE + c];
            acc.x = fmaf(xv.x, rv.x, acc.x);
            acc.y = fmaf(xv.y, rv.y, acc.y);
            acc.z = fmaf(xv.z, rv.z, acc.z);
            acc.w = fmaf(xv.w, rv.w, acc.w);
        }
        ++j;
    }
    return acc;
}

// hops 1-2: 1024-thread blocks (16 waves x 4 entities = 64-entity tiles),
// grid-stride, 512 resident blocks (2/CU, 32 waves/CU). fp16 output.
template<typename XS>
__global__ __launch_bounds__(HOP_TPB, 8)
void hop_mid_kernel(XS xs, const float4* __restrict__ rT4,
                    const int* __restrict__ row_ptr, const unsigned* __restrict__ packed,
                    uint2* __restrict__ yh, int nE, int nR) {
    __shared__ float4 r_lds[NRMAX * RSTRIDE];
    for (int i = threadIdx.x; i < nR * 16; i += HOP_TPB)
        r_lds[(i >> 4) * RSTRIDE + (i & 15)] = rT4[i];
    __syncthreads();
    int lane = threadIdx.x & 63;
    int g = lane >> 4, c = lane & 15;
    int wv = threadIdx.x >> 6;                   // 0..15
    int nTiles = (nE + 63) >> 6;
    for (int t = blockIdx.x; t < nTiles; t += gridDim.x) {
        int e = t * 64 + wv * 4 + g;
        float4 acc = hop_accum4(xs, r_lds, row_ptr, packed, e, g, c, nE);
        if (e < nE) yh[(size_t)e * 16 + c] = pack_half4(acc);
    }
}

// hop 3 fused with output transpose: 64-entity LDS tile, stores (B, N_E) fp32.
__global__ __launch_bounds__(HOP_TPB, 8)
void hop_out_kernel(F16Row xs, const float4* __restrict__ rT4,
                    const int* __restrict__ row_ptr, const unsigned* __restrict__ packed,
                    float* __restrict__ out, int nE, int nR) {
    __shared__ float4 r_lds[NRMAX * RSTRIDE];
    __shared__ float tile[64][65];
    for (int i = threadIdx.x; i < nR * 16; i += HOP_TPB)
        r_lds[(i >> 4) * RSTRIDE + (i & 15)] = rT4[i];
    __syncthreads();
    int lane = threadIdx.x & 63;
    int g = lane >> 4, c = lane & 15;
    int wv = threadIdx.x >> 6;                   // 0..15
    int nTiles = (nE + 63) >> 6;
    for (int t = blockIdx.x; t < nTiles; t += gridDim.x) {
        int e0 = t * 64;
        int ei = wv * 4 + g;                     // 0..63 unique per (wv,g)
        float4 acc = hop_accum4(xs, r_lds, row_ptr, packed, e0 + ei, g, c, nE);
        tile[ei][4 * c + 0] = acc.x;
        tile[ei][4 * c + 1] = acc.y;
        tile[ei][4 * c + 2] = acc.z;
        tile[ei][4 * c + 3] = acc.w;
        __syncthreads();
        #pragma unroll
        for (int k = 0; k < 4; ++k) {
            int b = wv * 4 + k;
            int e = e0 + lane;
            if (e < nE) out[(size_t)b * nE + e] = tile[lane][b];
        }
        __syncthreads();                         // tile reused next iteration
    }
}

extern "C" void kernel_launch(void* const* d_in, const int* in_sizes, int n_in,
                              void* d_out, int out_size, void* d_ws, size_t ws_size,
                              hipStream_t stream) {
    const float* x  = (const float*)d_in[0];
    const float* q  = (const float*)d_in[1];
    const float* W1 = (const float*)d_in[2];
    const float* b1 = (const float*)d_in[3];
    const float* W2 = (const float*)d_in[4];
    const float* b2 = (const float*)d_in[5];
    const float* W3 = (const float*)d_in[6];
    const float* b3 = (const float*)d_in[7];
    const int* subj = (const int*)d_in[8];
    const int* rel  = (const int*)d_in[9];
    const int* obj  = (const int*)d_in[10];
    // n_hop (d_in[11]) is the constant 3 per the reference; hops hardcoded.

    const int B     = 64;
    const int N_E   = in_sizes[0] / B;   // 200000
    const int N_W2V = in_sizes[1] / B;   // 300
    const int N_R   = in_sizes[3];       // 200
    const int N_T   = in_sizes[8];       // 1000000

    const size_t xelems = (size_t)N_E * B;
    const size_t xbytes = xelems * sizeof(float);

    // ws layout: [counts nE][row_ptr nE+4 (pad keeps rT 16B-aligned)][cursor nE]
    //            [packed nT][rT 3*N_R*64][bufA (fp32 xT)]
    // fp16 chain needs no extra ws: H1 = d_out scratch (25.6MB of 51.2MB),
    // H2 = bufA region (fp32 xT dead after hop1). hop3 reads H2, writes d_out
    // (H1 dead after hop2) -- regions disjoint, stream-serialized.
    int*      counts  = (int*)d_ws;
    int*      row_ptr = counts + N_E;
    int*      cursor  = row_ptr + (N_E + 4);
    unsigned* packed  = (unsigned*)(cursor + N_E);
    float*    rT      = (float*)(packed + N_T);          // 16B-aligned by construction
    float*    bufA    = rT + (size_t)3 * N_R * B;
    size_t used = (size_t)((char*)bufA - (char*)d_ws) + xbytes;

    uint2* H1 = (uint2*)d_out;
    uint2* H2 = (uint2*)bufA;

    // scan partials: steal tail of ws if free, else tail of packed (safe:
    // packed written only after scanC consumed partials).
    int nScan = (N_E + 255) / 256;       // 782
    int* partials = (int*)((char*)d_ws + ws_size - 4096);
    if ((size_t)((char*)partials - (char*)d_ws) < used)
        partials = (int*)packed + (N_T - 1024);

    // 1) r for all three layers
    {
        dim3 rgrid((3 * N_R + 63) / 64, B / 4);
        compute_r_kernel<<<rgrid, 256, 0, stream>>>(q, W1, b1, W2, b2, W3, b3, rT, N_R, N_W2V);
    }

    // 2) transpose x -> bufA
    int tgrid = (N_E + 63) / 64;
    transpose_in_kernel<<<tgrid, 256, 0, stream>>>(x, bufA, N_E);

    // 3) CSR build (XCD-sharded count -> scan -> XCD-sharded scatter)
    hipMemsetAsync(counts, 0, (size_t)N_E * sizeof(int), stream);
    count_kernel<<<1024, 256, 0, stream>>>(obj, counts, N_T, N_E);
    scanA_kernel<<<nScan, 256, 0, stream>>>(counts, partials, N_E);
    scanB_kernel<<<1, 1024, 0, stream>>>(partials, nScan);
    scanC_kernel<<<nScan, 256, 0, stream>>>(counts, partials, row_ptr, cursor, N_E);
    scatter_kernel<<<1024, 256, 0, stream>>>(subj, rel, obj, cursor, packed, N_T, N_E);

    // 4) three hops; hop3 fuses the output transpose
    int nTiles  = (N_E + 63) / 64;                 // 3125
    int hblocks = nTiles < HOP_BLOCKS ? nTiles : HOP_BLOCKS;
    hop_mid_kernel<F32Row><<<hblocks, HOP_TPB, 0, stream>>>(
        F32Row{(const float4*)bufA}, (const float4*)rT,
        row_ptr, packed, H1, N_E, N_R);
    hop_mid_kernel<F16Row><<<hblocks, HOP_TPB, 0, stream>>>(
        F16Row{(const uint2*)H1}, (const float4*)(rT + (size_t)1 * N_R * B),
        row_ptr, packed, H2, N_E, N_R);
    hop_out_kernel<<<hblocks, HOP_TPB, 0, stream>>>(
        F16Row{(const uint2*)H2}, (const float4*)(rT + (size_t)2 * N_R * B),
        row_ptr, packed, (float*)d_out, N_E, N_R);
}

// Round 4
// 385.407 us; speedup vs baseline: 1.1874x; 1.0081x over previous
//
#include <hip/hip_runtime.h>
#include <hip/hip_fp16.h>

#define WAVE 64
#define NXCD 8
#define NRMAX 200
#define RSTRIDE 17      // float4 units: 272B row stride -> per-rel start-bank offset 4*(rel%8)
#define HOP_TPB 1024
#define HOP_BLOCKS 512

// rT layout: [layer][N_R][64]  (batch innermost, matches lane)
__global__ void compute_r_kernel(const float* __restrict__ q,
                                 const float* __restrict__ W1, const float* __restrict__ b1,
                                 const float* __restrict__ W2, const float* __restrict__ b2,
                                 const float* __restrict__ W3, const float* __restrict__ b3,
                                 float* __restrict__ rT, int N_R, int N_W2V) {
    int lane = threadIdx.x & 63;
    int wv   = threadIdx.x >> 6;
    int b    = blockIdx.y * 4 + wv;
    int it   = blockIdx.x * 64 + lane;
    if (it >= 3 * N_R) return;
    int l = it / N_R;
    int j = it - l * N_R;
    const float* W  = (l == 0) ? W1 : (l == 1) ? W2 : W3;
    const float* bv = (l == 0) ? b1 : (l == 1) ? b2 : b3;
    const float* qrow = q + (size_t)b * N_W2V;
    float a0 = 0.f, a1 = 0.f, a2 = 0.f, a3 = 0.f;
    int k = 0;
    for (; k + 4 <= N_W2V; k += 4) {
        a0 = fmaf(qrow[k + 0], W[(size_t)(k + 0) * N_R + j], a0);
        a1 = fmaf(qrow[k + 1], W[(size_t)(k + 1) * N_R + j], a1);
        a2 = fmaf(qrow[k + 2], W[(size_t)(k + 2) * N_R + j], a2);
        a3 = fmaf(qrow[k + 3], W[(size_t)(k + 3) * N_R + j], a3);
    }
    for (; k < N_W2V; ++k)
        a0 = fmaf(qrow[k], W[(size_t)k * N_R + j], a0);
    rT[(size_t)it * WAVE + b] = bv[j] + ((a0 + a1) + (a2 + a3));
}

// R12: x (B=64, N_E) fp32 -> xT (N_E, 64) fp16. All hops gather 128B rows from
// a 25.6MB table. R3's bug: store read tile[ei][2j] (= x^T) instead of
// tile[2j][ei]; tile is written [batch][entity]. Fixed.
__global__ void transpose_in_f16_kernel(const float* __restrict__ in, __half2* __restrict__ out, int N_E) {
    __shared__ float tile[64][65];
    int e0 = blockIdx.x * 64;
    int li = threadIdx.x & 63;
    int lo = threadIdx.x >> 6;
    #pragma unroll
    for (int k = 0; k < 16; ++k) {
        int b = lo + 4 * k;
        int e = e0 + li;
        tile[b][li] = (e < N_E) ? in[(size_t)b * N_E + e] : 0.0f;
    }
    __syncthreads();
    #pragma unroll
    for (int k = 0; k < 8; ++k) {
        int idx = k * 256 + threadIdx.x;     // 0..2047
        int ei  = idx >> 5;                  // entity 0..63
        int j   = idx & 31;                  // half2 col (batch pair) 0..31
        int e   = e0 + ei;
        if (e < N_E)
            out[(size_t)e * 32 + j] = __floats2half2_rn(tile[2 * j][ei], tile[2 * j + 1][ei]);
    }
}

// ---- CSR build ----
// R5 lesson: un-sharded random 4B scatter writes cost 17x HBM write
// amplification (64B lines dirtied in multiple non-coherent XCD L2s).
// Group g = blockIdx%8 owns entity range; only touches its own slice.

__global__ void count_kernel(const int* __restrict__ obj, int* __restrict__ counts,
                             int nT, int nE) {
    int grp = blockIdx.x & (NXCD - 1);
    int sh  = (nE + NXCD - 1) / NXCD;
    int lo  = grp * sh;
    int hi  = min(nE, lo + sh);
    int tid    = (blockIdx.x >> 3) * blockDim.x + threadIdx.x;
    int stride = (gridDim.x >> 3) * blockDim.x;
    for (int t = tid; t < nT; t += stride) {
        int o = obj[t];
        if (o >= lo && o < hi) atomicAdd(&counts[o], 1);
    }
}

__global__ void scanA_kernel(const int* __restrict__ counts, int* __restrict__ partials, int nE) {
    __shared__ int lds[256];
    int i = blockIdx.x * 256 + threadIdx.x;
    lds[threadIdx.x] = (i < nE) ? counts[i] : 0;
    __syncthreads();
    for (int off = 128; off > 0; off >>= 1) {
        if (threadIdx.x < off) lds[threadIdx.x] += lds[threadIdx.x + off];
        __syncthreads();
    }
    if (threadIdx.x == 0) partials[blockIdx.x] = lds[0];
}

// single block, nP <= 1024 (here nP = ceil(200000/256) = 782)
__global__ void scanB_kernel(int* __restrict__ partials, int nP) {
    __shared__ int lds[1024];
    int tid = threadIdx.x;
    lds[tid] = (tid < nP) ? partials[tid] : 0;
    __syncthreads();
    for (int off = 1; off < 1024; off <<= 1) {
        int v = (tid >= off) ? lds[tid - off] : 0;
        __syncthreads();
        lds[tid] += v;
        __syncthreads();
    }
    if (tid < nP) partials[tid] = (tid == 0) ? 0 : lds[tid - 1];
}

__global__ void scanC_kernel(const int* __restrict__ counts, const int* __restrict__ partials,
                             int* __restrict__ row_ptr, int* __restrict__ cursor, int nE) {
    __shared__ int lds[256];
    int i = blockIdx.x * 256 + threadIdx.x;
    int c = (i < nE) ? counts[i] : 0;
    lds[threadIdx.x] = c;
    __syncthreads();
    for (int off = 1; off < 256; off <<= 1) {
        int v = (threadIdx.x >= off) ? lds[threadIdx.x - off] : 0;
        __syncthreads();
        lds[threadIdx.x] += v;
        __syncthreads();
    }
    int excl = partials[blockIdx.x] + ((threadIdx.x == 0) ? 0 : lds[threadIdx.x - 1]);
    if (i < nE) { row_ptr[i] = excl; cursor[i] = excl; }
    if (i == nE - 1) row_ptr[nE] = excl + c;
}

// packed = subj | (rel<<18). Valid for N_E < 2^18, N_R < 2^14 (here 200000/200).
__global__ void scatter_kernel(const int* __restrict__ subj, const int* __restrict__ rel,
                               const int* __restrict__ obj, int* __restrict__ cursor,
                               unsigned* __restrict__ packed, int nT, int nE) {
    int grp = blockIdx.x & (NXCD - 1);
    int sh  = (nE + NXCD - 1) / NXCD;
    int lo  = grp * sh;
    int hi  = min(nE, lo + sh);
    int tid    = (blockIdx.x >> 3) * blockDim.x + threadIdx.x;
    int stride = (gridDim.x >> 3) * blockDim.x;
    for (int t = tid; t < nT; t += stride) {
        int o = obj[t];
        if (o >= lo && o < hi) {
            int slot = atomicAdd(&cursor[o], 1);
            packed[slot] = (unsigned)subj[t] | ((unsigned)rel[t] << 18);
        }
    }
}

// R10: fp16 intermediates halved hop2/3 bytes (388us). R12: fp16 everywhere +
// unroll-8 issue-early gathers (still latency-limited at 3.5TB/s effective,
// occupancy 69%, nothing saturated -> more in-flight bytes per wave).

__device__ __forceinline__ float4 h4_to_f4(uint2 v) {
    float2 f0 = __half22float2(*(__half2*)&v.x);
    float2 f1 = __half22float2(*(__half2*)&v.y);
    return make_float4(f0.x, f0.y, f1.x, f1.y);
}

__device__ __forceinline__ uint2 pack_half4(float4 a) {
    __half2 h0 = __floats2half2_rn(a.x, a.y);
    __half2 h1 = __floats2half2_rn(a.z, a.w);
    uint2 v;
    v.x = *(unsigned*)&h0;
    v.y = *(unsigned*)&h1;
    return v;
}

// 4 entities/wave, 16 lanes x uint2 (8B) per fp16 entity row.
__device__ __forceinline__ float4 hop_accum4(const uint2* __restrict__ xp,
                                             const float4* __restrict__ r_lds,
                                             const int* __restrict__ row_ptr,
                                             const unsigned* __restrict__ packed,
                                             int e, int g, int c, int nE) {
    float4 acc = make_float4(0.f, 0.f, 0.f, 0.f);
    bool ev = e < nE;
    int beg = ev ? row_ptr[e] : 0;
    int end = ev ? row_ptr[e + 1] : 0;
    int len = end - beg;
    unsigned pv = (c < len) ? packed[beg + c] : 0u;   // stage first 16 idx of this group's bucket
    int n16 = min(len, 16);
    int m = max(n16, __shfl_xor(n16, 16));            // wave-max over the 4 groups
    m = max(m, __shfl_xor(m, 32));
    for (int j0 = 0; j0 < m; j0 += 8) {
        uint2 xv[8];
        unsigned pr[8];
        #pragma unroll
        for (int u = 0; u < 8; ++u) {                 // issue all 8 gathers first
            int jj = max(min(j0 + u, len - 1), 0);    // clamp: dup loads hit hot lines
            unsigned p = __shfl(pv, (g << 4) + jj);   // per-lane src index: group-local broadcast
            pr[u] = p >> 18;
            xv[u] = xp[(size_t)(p & 0x3FFFFu) * 16 + c];
        }
        #pragma unroll
        for (int u = 0; u < 8; ++u) {                 // consume with LDS-r FMAs
            if (j0 + u < len) {
                float4 rv = r_lds[pr[u] * RSTRIDE + c];
                float4 xf = h4_to_f4(xv[u]);
                acc.x = fmaf(xf.x, rv.x, acc.x);
                acc.y = fmaf(xf.y, rv.y, acc.y);
                acc.z = fmaf(xf.z, rv.z, acc.z);
                acc.w = fmaf(xf.w, rv.w, acc.w);
            }
        }
    }
    // rare overflow (len > 16): per-group sequential, wave votes to exit
    int j = 16;
    while (__any(j < len)) {
        if (j < len) {
            unsigned p = packed[beg + j];
            float4 xf = h4_to_f4(xp[(size_t)(p & 0x3FFFFu) * 16 + c]);
            float4 rv = r_lds[(p >> 18) * RSTRIDE + c];
            acc.x = fmaf(xf.x, rv.x, acc.x);
            acc.y = fmaf(xf.y, rv.y, acc.y);
            acc.z = fmaf(xf.z, rv.z, acc.z);
            acc.w = fmaf(xf.w, rv.w, acc.w);
        }
        ++j;
    }
    return acc;
}

// hops 1-2: 1024-thread blocks (16 waves x 4 entities = 64-entity tiles),
// grid-stride, 512 resident blocks (2/CU, 32 waves/CU). fp16 in, fp16 out.
__global__ __launch_bounds__(HOP_TPB, 8)
void hop_mid_kernel(const uint2* __restrict__ xp, const float4* __restrict__ rT4,
                    const int* __restrict__ row_ptr, const unsigned* __restrict__ packed,
                    uint2* __restrict__ yh, int nE, int nR) {
    __shared__ float4 r_lds[NRMAX * RSTRIDE];
    for (int i = threadIdx.x; i < nR * 16; i += HOP_TPB)
        r_lds[(i >> 4) * RSTRIDE + (i & 15)] = rT4[i];
    __syncthreads();
    int lane = threadIdx.x & 63;
    int g = lane >> 4, c = lane & 15;
    int wv = threadIdx.x >> 6;                   // 0..15
    int nTiles = (nE + 63) >> 6;
    for (int t = blockIdx.x; t < nTiles; t += gridDim.x) {
        int e = t * 64 + wv * 4 + g;
        float4 acc = hop_accum4(xp, r_lds, row_ptr, packed, e, g, c, nE);
        if (e < nE) yh[(size_t)e * 16 + c] = pack_half4(acc);
    }
}

// hop 3 fused with output transpose: 64-entity LDS tile, stores (B, N_E) fp32.
__global__ __launch_bounds__(HOP_TPB, 8)
void hop_out_kernel(const uint2* __restrict__ xp, const float4* __restrict__ rT4,
                    const int* __restrict__ row_ptr, const unsigned* __restrict__ packed,
                    float* __restrict__ out, int nE, int nR) {
    __shared__ float4 r_lds[NRMAX * RSTRIDE];
    __shared__ float tile[64][65];
    for (int i = threadIdx.x; i < nR * 16; i += HOP_TPB)
        r_lds[(i >> 4) * RSTRIDE + (i & 15)] = rT4[i];
    __syncthreads();
    int lane = threadIdx.x & 63;
    int g = lane >> 4, c = lane & 15;
    int wv = threadIdx.x >> 6;                   // 0..15
    int nTiles = (nE + 63) >> 6;
    for (int t = blockIdx.x; t < nTiles; t += gridDim.x) {
        int e0 = t * 64;
        int ei = wv * 4 + g;                     // 0..63 unique per (wv,g)
        float4 acc = hop_accum4(xp, r_lds, row_ptr, packed, e0 + ei, g, c, nE);
        tile[ei][4 * c + 0] = acc.x;
        tile[ei][4 * c + 1] = acc.y;
        tile[ei][4 * c + 2] = acc.z;
        tile[ei][4 * c + 3] = acc.w;
        __syncthreads();
        #pragma unroll
        for (int k = 0; k < 4; ++k) {
            int b = wv * 4 + k;
            int e = e0 + lane;
            if (e < nE) out[(size_t)b * nE + e] = tile[lane][b];
        }
        __syncthreads();                         // tile reused next iteration
    }
}

extern "C" void kernel_launch(void* const* d_in, const int* in_sizes, int n_in,
                              void* d_out, int out_size, void* d_ws, size_t ws_size,
                              hipStream_t stream) {
    const float* x  = (const float*)d_in[0];
    const float* q  = (const float*)d_in[1];
    const float* W1 = (const float*)d_in[2];
    const float* b1 = (const float*)d_in[3];
    const float* W2 = (const float*)d_in[4];
    const float* b2 = (const float*)d_in[5];
    const float* W3 = (const float*)d_in[6];
    const float* b3 = (const float*)d_in[7];
    const int* subj = (const int*)d_in[8];
    const int* rel  = (const int*)d_in[9];
    const int* obj  = (const int*)d_in[10];
    // n_hop (d_in[11]) is the constant 3 per the reference; hops hardcoded.

    const int B     = 64;
    const int N_E   = in_sizes[0] / B;   // 200000
    const int N_W2V = in_sizes[1] / B;   // 300
    const int N_R   = in_sizes[3];       // 200
    const int N_T   = in_sizes[8];       // 1000000

    const size_t h16bytes = (size_t)N_E * B * sizeof(__half);   // 25.6MB per fp16 buffer

    // ws layout: [counts nE][row_ptr nE+4 (pad keeps rT 16B-aligned)][cursor nE]
    //            [packed nT][rT 3*N_R*64][X0 fp16][H1 fp16]
    // H2 overwrites X0 (dead after hop1); hop3 reads H2, writes d_out.
    int*      counts  = (int*)d_ws;
    int*      row_ptr = counts + N_E;
    int*      cursor  = row_ptr + (N_E + 4);
    unsigned* packed  = (unsigned*)(cursor + N_E);
    float*    rT      = (float*)(packed + N_T);          // 16B-aligned by construction
    char*     X0      = (char*)(rT + (size_t)3 * N_R * B);
    size_t used = (size_t)(X0 - (char*)d_ws) + h16bytes;

    char* H1;
    if (ws_size >= used + h16bytes) {
        H1 = X0 + h16bytes;
        used += h16bytes;
    } else {
        H1 = (char*)d_out;   // 25.6MB scratch in the 51.2MB output; dead before hop3's write
    }
    char* H2 = X0;           // X0 dead after hop1

    // scan partials: steal tail of ws if free, else tail of packed (safe:
    // packed written only after scanC consumed partials).
    int nScan = (N_E + 255) / 256;       // 782
    int* partials = (int*)((char*)d_ws + ws_size - 4096);
    if ((size_t)((char*)partials - (char*)d_ws) < used)
        partials = (int*)packed + (N_T - 1024);

    // 1) r for all three layers
    {
        dim3 rgrid((3 * N_R + 63) / 64, B / 4);
        compute_r_kernel<<<rgrid, 256, 0, stream>>>(q, W1, b1, W2, b2, W3, b3, rT, N_R, N_W2V);
    }

    // 2) transpose x -> X0 (fp16)
    int tgrid = (N_E + 63) / 64;
    transpose_in_f16_kernel<<<tgrid, 256, 0, stream>>>(x, (__half2*)X0, N_E);

    // 3) CSR build (XCD-sharded count -> scan -> XCD-sharded scatter)
    hipMemsetAsync(counts, 0, (size_t)N_E * sizeof(int), stream);
    count_kernel<<<1024, 256, 0, stream>>>(obj, counts, N_T, N_E);
    scanA_kernel<<<nScan, 256, 0, stream>>>(counts, partials, N_E);
    scanB_kernel<<<1, 1024, 0, stream>>>(partials, nScan);
    scanC_kernel<<<nScan, 256, 0, stream>>>(counts, partials, row_ptr, cursor, N_E);
    scatter_kernel<<<1024, 256, 0, stream>>>(subj, rel, obj, cursor, packed, N_T, N_E);

    // 4) three hops; hop3 fuses the output transpose
    int nTiles  = (N_E + 63) / 64;                 // 3125
    int hblocks = nTiles < HOP_BLOCKS ? nTiles : HOP_BLOCKS;
    hop_mid_kernel<<<hblocks, HOP_TPB, 0, stream>>>(
        (const uint2*)X0, (const float4*)rT,
        row_ptr, packed, (uint2*)H1, N_E, N_R);
    hop_mid_kernel<<<hblocks, HOP_TPB, 0, stream>>>(
        (const uint2*)H1, (const float4*)(rT + (size_t)1 * N_R * B),
        row_ptr, packed, (uint2*)H2, N_E, N_R);
    hop_out_kernel<<<hblocks, HOP_TPB, 0, stream>>>(
        (const uint2*)H2, (const float4*)(rT + (size_t)2 * N_R * B),
        row_ptr, packed, (float*)d_out, N_E, N_R);
}

// Round 5
// 377.419 us; speedup vs baseline: 1.2125x; 1.0212x over previous
//
#include <hip/hip_runtime.h>
#include <hip/hip_fp16.h>

#define WAVE 64
#define NXCD 8
#define NRMAX 200
#define RSTRIDE 17      // float4 units: 272B row stride -> per-rel start-bank offset 4*(rel%8)
#define HOP_TPB 1024
#define HOP_BLOCKS 512
#define CSR_BLOCKS 2048
#define CSR_TPB 256

// rT layout: [layer][N_R][64]  (batch innermost, matches lane)
__global__ void compute_r_kernel(const float* __restrict__ q,
                                 const float* __restrict__ W1, const float* __restrict__ b1,
                                 const float* __restrict__ W2, const float* __restrict__ b2,
                                 const float* __restrict__ W3, const float* __restrict__ b3,
                                 float* __restrict__ rT, int N_R, int N_W2V) {
    int lane = threadIdx.x & 63;
    int wv   = threadIdx.x >> 6;
    int b    = blockIdx.y * 4 + wv;
    int it   = blockIdx.x * 64 + lane;
    if (it >= 3 * N_R) return;
    int l = it / N_R;
    int j = it - l * N_R;
    const float* W  = (l == 0) ? W1 : (l == 1) ? W2 : W3;
    const float* bv = (l == 0) ? b1 : (l == 1) ? b2 : b3;
    const float* qrow = q + (size_t)b * N_W2V;
    float a0 = 0.f, a1 = 0.f, a2 = 0.f, a3 = 0.f;
    int k = 0;
    for (; k + 4 <= N_W2V; k += 4) {
        a0 = fmaf(qrow[k + 0], W[(size_t)(k + 0) * N_R + j], a0);
        a1 = fmaf(qrow[k + 1], W[(size_t)(k + 1) * N_R + j], a1);
        a2 = fmaf(qrow[k + 2], W[(size_t)(k + 2) * N_R + j], a2);
        a3 = fmaf(qrow[k + 3], W[(size_t)(k + 3) * N_R + j], a3);
    }
    for (; k < N_W2V; ++k)
        a0 = fmaf(qrow[k], W[(size_t)k * N_R + j], a0);
    rT[(size_t)it * WAVE + b] = bv[j] + ((a0 + a1) + (a2 + a3));
}

// x (B=64, N_E) fp32 -> xT (N_E, 64) fp16. tile is written [batch][entity];
// fp16 store must read tile[2j][ei] (R3 bug was the swap).
__global__ void transpose_in_f16_kernel(const float* __restrict__ in, __half2* __restrict__ out, int N_E) {
    __shared__ float tile[64][65];
    int e0 = blockIdx.x * 64;
    int li = threadIdx.x & 63;
    int lo = threadIdx.x >> 6;
    #pragma unroll
    for (int k = 0; k < 16; ++k) {
        int b = lo + 4 * k;
        int e = e0 + li;
        tile[b][li] = (e < N_E) ? in[(size_t)b * N_E + e] : 0.0f;
    }
    __syncthreads();
    #pragma unroll
    for (int k = 0; k < 8; ++k) {
        int idx = k * 256 + threadIdx.x;     // 0..2047
        int ei  = idx >> 5;                  // entity 0..63
        int j   = idx & 31;                  // half2 col (batch pair) 0..31
        int e   = e0 + ei;
        if (e < N_E)
            out[(size_t)e * 32 + j] = __floats2half2_rn(tile[2 * j][ei], tile[2 * j + 1][ei]);
    }
}

// ---- CSR build ----
// R5 lesson: un-sharded random 4B scatter writes cost 17x HBM write
// amplification (64B lines dirtied in multiple non-coherent XCD L2s).
// Group g = blockIdx%8 owns entity range; only touches its own slice.
// R13: scatter was latency-bound (1.8TB/s, 4.7% VALU, 37% occupancy), not
// byte-bound. 2x grid (32 waves/CU ceiling), int4 obj loads (4x fewer load
// instrs), and pre-packed subj|rel so the per-match chain is one 4B load.

// fused: pack (full grid, coalesced) + XCD-sharded count
__global__ void count_pack_kernel(const int* __restrict__ subj, const int* __restrict__ rel,
                                  const int* __restrict__ obj,
                                  unsigned* __restrict__ packed_all,
                                  int* __restrict__ counts, int nT, int nE) {
    int nT4 = nT >> 2;
    // pack subj|rel<<18, int4-vectorized over the whole grid
    {
        int gtid    = blockIdx.x * blockDim.x + threadIdx.x;
        int gstride = gridDim.x * blockDim.x;
        for (int t = gtid; t < nT4; t += gstride) {
            int4 s = ((const int4*)subj)[t];
            int4 r = ((const int4*)rel)[t];
            uint4 p;
            p.x = (unsigned)s.x | ((unsigned)r.x << 18);
            p.y = (unsigned)s.y | ((unsigned)r.y << 18);
            p.z = (unsigned)s.z | ((unsigned)r.z << 18);
            p.w = (unsigned)s.w | ((unsigned)r.w << 18);
            ((uint4*)packed_all)[t] = p;
        }
        for (int t = nT4 * 4 + gtid; t < nT; t += gstride)
            packed_all[t] = (unsigned)subj[t] | ((unsigned)rel[t] << 18);
    }
    // XCD-sharded count, int4 obj loads
    int grp = blockIdx.x & (NXCD - 1);
    int sh  = (nE + NXCD - 1) / NXCD;
    int lo  = grp * sh;
    int hi  = min(nE, lo + sh);
    int tid    = (blockIdx.x >> 3) * blockDim.x + threadIdx.x;
    int stride = (gridDim.x >> 3) * blockDim.x;
    for (int t = tid; t < nT4; t += stride) {
        int4 o = ((const int4*)obj)[t];
        if (o.x >= lo && o.x < hi) atomicAdd(&counts[o.x], 1);
        if (o.y >= lo && o.y < hi) atomicAdd(&counts[o.y], 1);
        if (o.z >= lo && o.z < hi) atomicAdd(&counts[o.z], 1);
        if (o.w >= lo && o.w < hi) atomicAdd(&counts[o.w], 1);
    }
    for (int t = nT4 * 4 + tid; t < nT; t += stride) {
        int o = obj[t];
        if (o >= lo && o < hi) atomicAdd(&counts[o], 1);
    }
}

__global__ void scanA_kernel(const int* __restrict__ counts, int* __restrict__ partials, int nE) {
    __shared__ int lds[256];
    int i = blockIdx.x * 256 + threadIdx.x;
    lds[threadIdx.x] = (i < nE) ? counts[i] : 0;
    __syncthreads();
    for (int off = 128; off > 0; off >>= 1) {
        if (threadIdx.x < off) lds[threadIdx.x] += lds[threadIdx.x + off];
        __syncthreads();
    }
    if (threadIdx.x == 0) partials[blockIdx.x] = lds[0];
}

// single block, nP <= 1024 (here nP = ceil(200000/256) = 782)
__global__ void scanB_kernel(int* __restrict__ partials, int nP) {
    __shared__ int lds[1024];
    int tid = threadIdx.x;
    lds[tid] = (tid < nP) ? partials[tid] : 0;
    __syncthreads();
    for (int off = 1; off < 1024; off <<= 1) {
        int v = (tid >= off) ? lds[tid - off] : 0;
        __syncthreads();
        lds[tid] += v;
        __syncthreads();
    }
    if (tid < nP) partials[tid] = (tid == 0) ? 0 : lds[tid - 1];
}

__global__ void scanC_kernel(const int* __restrict__ counts, const int* __restrict__ partials,
                             int* __restrict__ row_ptr, int* __restrict__ cursor, int nE) {
    __shared__ int lds[256];
    int i = blockIdx.x * 256 + threadIdx.x;
    int c = (i < nE) ? counts[i] : 0;
    lds[threadIdx.x] = c;
    __syncthreads();
    for (int off = 1; off < 256; off <<= 1) {
        int v = (threadIdx.x >= off) ? lds[threadIdx.x - off] : 0;
        __syncthreads();
        lds[threadIdx.x] += v;
        __syncthreads();
    }
    int excl = partials[blockIdx.x] + ((threadIdx.x == 0) ? 0 : lds[threadIdx.x - 1]);
    if (i < nE) { row_ptr[i] = excl; cursor[i] = excl; }
    if (i == nE - 1) row_ptr[nE] = excl + c;
}

// packed = subj | (rel<<18). Valid for N_E < 2^18, N_R < 2^14 (here 200000/200).
__global__ void scatter_kernel(const int* __restrict__ obj, const unsigned* __restrict__ packed_all,
                               int* __restrict__ cursor, unsigned* __restrict__ packed,
                               int nT, int nE) {
    int grp = blockIdx.x & (NXCD - 1);
    int sh  = (nE + NXCD - 1) / NXCD;
    int lo  = grp * sh;
    int hi  = min(nE, lo + sh);
    int tid    = (blockIdx.x >> 3) * blockDim.x + threadIdx.x;
    int stride = (gridDim.x >> 3) * blockDim.x;
    int nT4 = nT >> 2;
    for (int t = tid; t < nT4; t += stride) {
        int4 o = ((const int4*)obj)[t];
        int base = t * 4;
        if (o.x >= lo && o.x < hi) { int s_ = atomicAdd(&cursor[o.x], 1); packed[s_] = packed_all[base + 0]; }
        if (o.y >= lo && o.y < hi) { int s_ = atomicAdd(&cursor[o.y], 1); packed[s_] = packed_all[base + 1]; }
        if (o.z >= lo && o.z < hi) { int s_ = atomicAdd(&cursor[o.z], 1); packed[s_] = packed_all[base + 2]; }
        if (o.w >= lo && o.w < hi) { int s_ = atomicAdd(&cursor[o.w], 1); packed[s_] = packed_all[base + 3]; }
    }
    for (int t = nT4 * 4 + tid; t < nT; t += stride) {
        int o = obj[t];
        if (o >= lo && o < hi) {
            int s_ = atomicAdd(&cursor[o], 1);
            packed[s_] = packed_all[t];
        }
    }
}

// ---- hops ----
// R10: fp16 intermediates halved hop2/3 bytes. R12: fp16 x0 + unroll-8
// issue-early gathers. R13 analysis: gather FETCH (~105MB/hop) matches the
// distinct-line floor (1-e^-0.625)*25.6MB*8 XCDs ~ 95MB -> hops are at the
// structural floor for random gathers; only subj-sorted reordering beats it.

__device__ __forceinline__ float4 h4_to_f4(uint2 v) {
    float2 f0 = __half22float2(*(__half2*)&v.x);
    float2 f1 = __half22float2(*(__half2*)&v.y);
    return make_float4(f0.x, f0.y, f1.x, f1.y);
}

__device__ __forceinline__ uint2 pack_half4(float4 a) {
    __half2 h0 = __floats2half2_rn(a.x, a.y);
    __half2 h1 = __floats2half2_rn(a.z, a.w);
    uint2 v;
    v.x = *(unsigned*)&h0;
    v.y = *(unsigned*)&h1;
    return v;
}

// 4 entities/wave, 16 lanes x uint2 (8B) per fp16 entity row.
__device__ __forceinline__ float4 hop_accum4(const uint2* __restrict__ xp,
                                             const float4* __restrict__ r_lds,
                                             const int* __restrict__ row_ptr,
                                             const unsigned* __restrict__ packed,
                                             int e, int g, int c, int nE) {
    float4 acc = make_float4(0.f, 0.f, 0.f, 0.f);
    bool ev = e < nE;
    int beg = ev ? row_ptr[e] : 0;
    int end = ev ? row_ptr[e + 1] : 0;
    int len = end - beg;
    unsigned pv = (c < len) ? packed[beg + c] : 0u;   // stage first 16 idx of this group's bucket
    int n16 = min(len, 16);
    int m = max(n16, __shfl_xor(n16, 16));            // wave-max over the 4 groups
    m = max(m, __shfl_xor(m, 32));
    for (int j0 = 0; j0 < m; j0 += 8) {
        uint2 xv[8];
        unsigned pr[8];
        #pragma unroll
        for (int u = 0; u < 8; ++u) {                 // issue all 8 gathers first
            int jj = max(min(j0 + u, len - 1), 0);    // clamp: dup loads hit hot lines
            unsigned p = __shfl(pv, (g << 4) + jj);   // per-lane src index: group-local broadcast
            pr[u] = p >> 18;
            xv[u] = xp[(size_t)(p & 0x3FFFFu) * 16 + c];
        }
        #pragma unroll
        for (int u = 0; u < 8; ++u) {                 // consume with LDS-r FMAs
            if (j0 + u < len) {
                float4 rv = r_lds[pr[u] * RSTRIDE + c];
                float4 xf = h4_to_f4(xv[u]);
                acc.x = fmaf(xf.x, rv.x, acc.x);
                acc.y = fmaf(xf.y, rv.y, acc.y);
                acc.z = fmaf(xf.z, rv.z, acc.z);
                acc.w = fmaf(xf.w, rv.w, acc.w);
            }
        }
    }
    // rare overflow (len > 16): per-group sequential, wave votes to exit
    int j = 16;
    while (__any(j < len)) {
        if (j < len) {
            unsigned p = packed[beg + j];
            float4 xf = h4_to_f4(xp[(size_t)(p & 0x3FFFFu) * 16 + c]);
            float4 rv = r_lds[(p >> 18) * RSTRIDE + c];
            acc.x = fmaf(xf.x, rv.x, acc.x);
            acc.y = fmaf(xf.y, rv.y, acc.y);
            acc.z = fmaf(xf.z, rv.z, acc.z);
            acc.w = fmaf(xf.w, rv.w, acc.w);
        }
        ++j;
    }
    return acc;
}

// hops 1-2: 1024-thread blocks (16 waves x 4 entities = 64-entity tiles),
// grid-stride, 512 resident blocks (2/CU, 32 waves/CU). fp16 in, fp16 out.
__global__ __launch_bounds__(HOP_TPB, 8)
void hop_mid_kernel(const uint2* __restrict__ xp, const float4* __restrict__ rT4,
                    const int* __restrict__ row_ptr, const unsigned* __restrict__ packed,
                    uint2* __restrict__ yh, int nE, int nR) {
    __shared__ float4 r_lds[NRMAX * RSTRIDE];
    for (int i = threadIdx.x; i < nR * 16; i += HOP_TPB)
        r_lds[(i >> 4) * RSTRIDE + (i & 15)] = rT4[i];
    __syncthreads();
    int lane = threadIdx.x & 63;
    int g = lane >> 4, c = lane & 15;
    int wv = threadIdx.x >> 6;                   // 0..15
    int nTiles = (nE + 63) >> 6;
    for (int t = blockIdx.x; t < nTiles; t += gridDim.x) {
        int e = t * 64 + wv * 4 + g;
        float4 acc = hop_accum4(xp, r_lds, row_ptr, packed, e, g, c, nE);
        if (e < nE) yh[(size_t)e * 16 + c] = pack_half4(acc);
    }
}

// hop 3 fused with output transpose: 64-entity LDS tile, stores (B, N_E) fp32.
__global__ __launch_bounds__(HOP_TPB, 8)
void hop_out_kernel(const uint2* __restrict__ xp, const float4* __restrict__ rT4,
                    const int* __restrict__ row_ptr, const unsigned* __restrict__ packed,
                    float* __restrict__ out, int nE, int nR) {
    __shared__ float4 r_lds[NRMAX * RSTRIDE];
    __shared__ float tile[64][65];
    for (int i = threadIdx.x; i < nR * 16; i += HOP_TPB)
        r_lds[(i >> 4) * RSTRIDE + (i & 15)] = rT4[i];
    __syncthreads();
    int lane = threadIdx.x & 63;
    int g = lane >> 4, c = lane & 15;
    int wv = threadIdx.x >> 6;                   // 0..15
    int nTiles = (nE + 63) >> 6;
    for (int t = blockIdx.x; t < nTiles; t += gridDim.x) {
        int e0 = t * 64;
        int ei = wv * 4 + g;                     // 0..63 unique per (wv,g)
        float4 acc = hop_accum4(xp, r_lds, row_ptr, packed, e0 + ei, g, c, nE);
        tile[ei][4 * c + 0] = acc.x;
        tile[ei][4 * c + 1] = acc.y;
        tile[ei][4 * c + 2] = acc.z;
        tile[ei][4 * c + 3] = acc.w;
        __syncthreads();
        #pragma unroll
        for (int k = 0; k < 4; ++k) {
            int b = wv * 4 + k;
            int e = e0 + lane;
            if (e < nE) out[(size_t)b * nE + e] = tile[lane][b];
        }
        __syncthreads();                         // tile reused next iteration
    }
}

extern "C" void kernel_launch(void* const* d_in, const int* in_sizes, int n_in,
                              void* d_out, int out_size, void* d_ws, size_t ws_size,
                              hipStream_t stream) {
    const float* x  = (const float*)d_in[0];
    const float* q  = (const float*)d_in[1];
    const float* W1 = (const float*)d_in[2];
    const float* b1 = (const float*)d_in[3];
    const float* W2 = (const float*)d_in[4];
    const float* b2 = (const float*)d_in[5];
    const float* W3 = (const float*)d_in[6];
    const float* b3 = (const float*)d_in[7];
    const int* subj = (const int*)d_in[8];
    const int* rel  = (const int*)d_in[9];
    const int* obj  = (const int*)d_in[10];
    // n_hop (d_in[11]) is the constant 3 per the reference; hops hardcoded.

    const int B     = 64;
    const int N_E   = in_sizes[0] / B;   // 200000
    const int N_W2V = in_sizes[1] / B;   // 300
    const int N_R   = in_sizes[3];       // 200
    const int N_T   = in_sizes[8];       // 1000000

    const size_t h16bytes = (size_t)N_E * B * sizeof(__half);   // 25.6MB per fp16 buffer

    // ws layout: [counts nE][row_ptr nE+4 (pad keeps rT 16B-aligned)][cursor nE]
    //            [packed nT][rT 3*N_R*64][X0 fp16][H1 fp16?][packed_all?]
    // H2 overwrites X0 (dead after hop1); hop3 reads H2, writes d_out.
    int*      counts  = (int*)d_ws;
    int*      row_ptr = counts + N_E;
    int*      cursor  = row_ptr + (N_E + 4);
    unsigned* packed  = (unsigned*)(cursor + N_E);
    float*    rT      = (float*)(packed + N_T);          // 16B-aligned by construction
    char*     X0      = (char*)(rT + (size_t)3 * N_R * B);
    size_t used = (size_t)(X0 - (char*)d_ws) + h16bytes;

    char* H1;
    if (ws_size >= used + h16bytes) {
        H1 = X0 + h16bytes;
        used += h16bytes;
    } else {
        H1 = (char*)d_out;   // 25.6MB scratch in the 51.2MB output; dead before hop3's write
    }
    char* H2 = X0;           // X0 dead after hop1

    // packed_all (subj|rel<<18, triple order): ws if it fits, else the upper
    // half of d_out (beyond H1's 25.6MB; consumed by scatter long before
    // hop3's full overwrite of d_out).
    unsigned* packed_all;
    if (ws_size >= used + (size_t)N_T * sizeof(unsigned)) {
        packed_all = (unsigned*)((char*)d_ws + used);
        used += (size_t)N_T * sizeof(unsigned);
    } else {
        packed_all = (unsigned*)((char*)d_out + h16bytes);
    }

    // scan partials: steal tail of ws if free, else tail of packed (safe:
    // packed written only after scanC consumed partials).
    int nScan = (N_E + 255) / 256;       // 782
    int* partials = (int*)((char*)d_ws + ws_size - 4096);
    if ((size_t)((char*)partials - (char*)d_ws) < used)
        partials = (int*)packed + (N_T - 1024);

    // 1) r for all three layers
    {
        dim3 rgrid((3 * N_R + 63) / 64, B / 4);
        compute_r_kernel<<<rgrid, 256, 0, stream>>>(q, W1, b1, W2, b2, W3, b3, rT, N_R, N_W2V);
    }

    // 2) transpose x -> X0 (fp16)
    int tgrid = (N_E + 63) / 64;
    transpose_in_f16_kernel<<<tgrid, 256, 0, stream>>>(x, (__half2*)X0, N_E);

    // 3) CSR build (pack + XCD-sharded count -> scan -> XCD-sharded scatter)
    hipMemsetAsync(counts, 0, (size_t)N_E * sizeof(int), stream);
    count_pack_kernel<<<CSR_BLOCKS, CSR_TPB, 0, stream>>>(subj, rel, obj, packed_all, counts, N_T, N_E);
    scanA_kernel<<<nScan, 256, 0, stream>>>(counts, partials, N_E);
    scanB_kernel<<<1, 1024, 0, stream>>>(partials, nScan);
    scanC_kernel<<<nScan, 256, 0, stream>>>(counts, partials, row_ptr, cursor, N_E);
    scatter_kernel<<<CSR_BLOCKS, CSR_TPB, 0, stream>>>(obj, packed_all, cursor, packed, N_T, N_E);

    // 4) three hops; hop3 fuses the output transpose
    int nTiles  = (N_E + 63) / 64;                 // 3125
    int hblocks = nTiles < HOP_BLOCKS ? nTiles : HOP_BLOCKS;
    hop_mid_kernel<<<hblocks, HOP_TPB, 0, stream>>>(
        (const uint2*)X0, (const float4*)rT,
        row_ptr, packed, (uint2*)H1, N_E, N_R);
    hop_mid_kernel<<<hblocks, HOP_TPB, 0, stream>>>(
        (const uint2*)H1, (const float4*)(rT + (size_t)1 * N_R * B),
        row_ptr, packed, (uint2*)H2, N_E, N_R);
    hop_out_kernel<<<hblocks, HOP_TPB, 0, stream>>>(
        (const uint2*)H2, (const float4*)(rT + (size_t)2 * N_R * B),
        row_ptr, packed, (float*)d_out, N_E, N_R);
}

// Round 6
// 354.064 us; speedup vs baseline: 1.2925x; 1.0660x over previous
//
#include <hip/hip_runtime.h>
#include <hip/hip_fp16.h>

#define WAVE 64
#define NXCD 8
#define NRMAX 200
#define RSTRIDE 17      // float4 units: 272B row stride -> per-rel start-bank offset 4*(rel%8)
#define HOP_TPB 1024
#define HOP_BLOCKS 512
#define CSR_BLOCKS 2048
#define CSR_TPB 256
#define CAP 16          // slots per entity; P(Poisson(5)>16)~1.4e-5 -> ~3 ovf triples/run
#define OVF_CAP 32768

// rT layout: [layer][N_R][64]  (batch innermost, matches lane)
__global__ void compute_r_kernel(const float* __restrict__ q,
                                 const float* __restrict__ W1, const float* __restrict__ b1,
                                 const float* __restrict__ W2, const float* __restrict__ b2,
                                 const float* __restrict__ W3, const float* __restrict__ b3,
                                 float* __restrict__ rT, int N_R, int N_W2V) {
    int lane = threadIdx.x & 63;
    int wv   = threadIdx.x >> 6;
    int b    = blockIdx.y * 4 + wv;
    int it   = blockIdx.x * 64 + lane;
    if (it >= 3 * N_R) return;
    int l = it / N_R;
    int j = it - l * N_R;
    const float* W  = (l == 0) ? W1 : (l == 1) ? W2 : W3;
    const float* bv = (l == 0) ? b1 : (l == 1) ? b2 : b3;
    const float* qrow = q + (size_t)b * N_W2V;
    float a0 = 0.f, a1 = 0.f, a2 = 0.f, a3 = 0.f;
    int k = 0;
    for (; k + 4 <= N_W2V; k += 4) {
        a0 = fmaf(qrow[k + 0], W[(size_t)(k + 0) * N_R + j], a0);
        a1 = fmaf(qrow[k + 1], W[(size_t)(k + 1) * N_R + j], a1);
        a2 = fmaf(qrow[k + 2], W[(size_t)(k + 2) * N_R + j], a2);
        a3 = fmaf(qrow[k + 3], W[(size_t)(k + 3) * N_R + j], a3);
    }
    for (; k < N_W2V; ++k)
        a0 = fmaf(qrow[k], W[(size_t)k * N_R + j], a0);
    rT[(size_t)it * WAVE + b] = bv[j] + ((a0 + a1) + (a2 + a3));
}

// x (B=64, N_E) fp32 -> xT (N_E, 64) fp16. tile is written [batch][entity];
// fp16 store must read tile[2j][ei] (R3 bug was the swap).
__global__ void transpose_in_f16_kernel(const float* __restrict__ in, __half2* __restrict__ out, int N_E) {
    __shared__ float tile[64][65];
    int e0 = blockIdx.x * 64;
    int li = threadIdx.x & 63;
    int lo = threadIdx.x >> 6;
    #pragma unroll
    for (int k = 0; k < 16; ++k) {
        int b = lo + 4 * k;
        int e = e0 + li;
        tile[b][li] = (e < N_E) ? in[(size_t)b * N_E + e] : 0.0f;
    }
    __syncthreads();
    #pragma unroll
    for (int k = 0; k < 8; ++k) {
        int idx = k * 256 + threadIdx.x;     // 0..2047
        int ei  = idx >> 5;                  // entity 0..63
        int j   = idx & 31;                  // half2 col (batch pair) 0..31
        int e   = e0 + ei;
        if (e < N_E)
            out[(size_t)e * 32 + j] = __floats2half2_rn(tile[2 * j][ei], tile[2 * j + 1][ei]);
    }
}

// ---- bucket build (R14) ----
// R5 lesson: un-sharded random 4B scatter writes cost 17x HBM write
// amplification; XCD group only touches its own entity slice.
// R14: count pass + 3 scans eliminated. Fixed-capacity direct scatter:
// slot = atomicAdd(cnt[obj]); slot < CAP -> slots[obj*CAP+slot], else
// overflow list (expected ~3 entries; merged post-hop by ovf kernels).
// One atomic pass instead of two + scans.

__global__ void scatter_direct_kernel(const int* __restrict__ subj, const int* __restrict__ rel,
                                      const int* __restrict__ obj,
                                      int* __restrict__ cnt, unsigned* __restrict__ slots,
                                      int* __restrict__ novf, int* __restrict__ ovf_obj,
                                      unsigned* __restrict__ ovf_pk, int nT, int nE) {
    int grp = blockIdx.x & (NXCD - 1);
    int sh  = (nE + NXCD - 1) / NXCD;
    int lo  = grp * sh;
    int hi  = min(nE, lo + sh);
    int tid    = (blockIdx.x >> 3) * blockDim.x + threadIdx.x;
    int stride = (gridDim.x >> 3) * blockDim.x;
    int nT4 = nT >> 2;
    for (int t = tid; t < nT4; t += stride) {
        int4 o = ((const int4*)obj)[t];
        int base = t * 4;
        #pragma unroll
        for (int u = 0; u < 4; ++u) {
            int oo = (u == 0) ? o.x : (u == 1) ? o.y : (u == 2) ? o.z : o.w;
            if (oo >= lo && oo < hi) {
                unsigned pk = (unsigned)subj[base + u] | ((unsigned)rel[base + u] << 18);
                int slot = atomicAdd(&cnt[oo], 1);
                if (slot < CAP) slots[(size_t)oo * CAP + slot] = pk;
                else {
                    int oi = atomicAdd(novf, 1);
                    if (oi < OVF_CAP) { ovf_obj[oi] = oo; ovf_pk[oi] = pk; }
                }
            }
        }
    }
    for (int t = nT4 * 4 + tid; t < nT; t += stride) {
        int oo = obj[t];
        if (oo >= lo && oo < hi) {
            unsigned pk = (unsigned)subj[t] | ((unsigned)rel[t] << 18);
            int slot = atomicAdd(&cnt[oo], 1);
            if (slot < CAP) slots[(size_t)oo * CAP + slot] = pk;
            else {
                int oi = atomicAdd(novf, 1);
                if (oi < OVF_CAP) { ovf_obj[oi] = oo; ovf_pk[oi] = pk; }
            }
        }
    }
}

// ---- hops ----
// R10: fp16 intermediates. R12: fp16 x0 + unroll-8 issue-early gathers.
// R13: gather FETCH matches the distinct-line floor -> hops treated as
// random-access-BW bound (~3.5TB/s); left unchanged as control this round.
// R14: bucket = slots[e*CAP .. e*CAP+min(cnt[e],CAP)), one 64B line; the
// len>16 tail loop is gone (overflow handled by ovf kernels post-hop).

__device__ __forceinline__ float4 h4_to_f4(uint2 v) {
    float2 f0 = __half22float2(*(__half2*)&v.x);
    float2 f1 = __half22float2(*(__half2*)&v.y);
    return make_float4(f0.x, f0.y, f1.x, f1.y);
}

__device__ __forceinline__ uint2 pack_half4(float4 a) {
    __half2 h0 = __floats2half2_rn(a.x, a.y);
    __half2 h1 = __floats2half2_rn(a.z, a.w);
    uint2 v;
    v.x = *(unsigned*)&h0;
    v.y = *(unsigned*)&h1;
    return v;
}

// 4 entities/wave, 16 lanes x uint2 (8B) per fp16 entity row.
__device__ __forceinline__ float4 hop_accum4(const uint2* __restrict__ xp,
                                             const float4* __restrict__ r_lds,
                                             const int* __restrict__ cnt,
                                             const unsigned* __restrict__ slots,
                                             int e, int g, int c, int nE) {
    float4 acc = make_float4(0.f, 0.f, 0.f, 0.f);
    int len = (e < nE) ? min(cnt[e], CAP) : 0;
    unsigned pv = (c < len) ? slots[(size_t)e * CAP + c] : 0u;  // whole bucket = one 64B line
    int m = max(len, __shfl_xor(len, 16));            // wave-max over the 4 groups
    m = max(m, __shfl_xor(m, 32));
    for (int j0 = 0; j0 < m; j0 += 8) {
        uint2 xv[8];
        unsigned pr[8];
        #pragma unroll
        for (int u = 0; u < 8; ++u) {                 // issue all 8 gathers first
            int jj = max(min(j0 + u, len - 1), 0);    // clamp: dup loads hit hot lines
            unsigned p = __shfl(pv, (g << 4) + jj);   // per-lane src index: group-local broadcast
            pr[u] = p >> 18;
            xv[u] = xp[(size_t)(p & 0x3FFFFu) * 16 + c];
        }
        #pragma unroll
        for (int u = 0; u < 8; ++u) {                 // consume with LDS-r FMAs
            if (j0 + u < len) {
                float4 rv = r_lds[pr[u] * RSTRIDE + c];
                float4 xf = h4_to_f4(xv[u]);
                acc.x = fmaf(xf.x, rv.x, acc.x);
                acc.y = fmaf(xf.y, rv.y, acc.y);
                acc.z = fmaf(xf.z, rv.z, acc.z);
                acc.w = fmaf(xf.w, rv.w, acc.w);
            }
        }
    }
    return acc;
}

// hops 1-2: 1024-thread blocks (16 waves x 4 entities = 64-entity tiles),
// grid-stride, 512 resident blocks (2/CU, 32 waves/CU). fp16 in, fp16 out.
__global__ __launch_bounds__(HOP_TPB, 8)
void hop_mid_kernel(const uint2* __restrict__ xp, const float4* __restrict__ rT4,
                    const int* __restrict__ cnt, const unsigned* __restrict__ slots,
                    uint2* __restrict__ yh, int nE, int nR) {
    __shared__ float4 r_lds[NRMAX * RSTRIDE];
    for (int i = threadIdx.x; i < nR * 16; i += HOP_TPB)
        r_lds[(i >> 4) * RSTRIDE + (i & 15)] = rT4[i];
    __syncthreads();
    int lane = threadIdx.x & 63;
    int g = lane >> 4, c = lane & 15;
    int wv = threadIdx.x >> 6;                   // 0..15
    int nTiles = (nE + 63) >> 6;
    for (int t = blockIdx.x; t < nTiles; t += gridDim.x) {
        int e = t * 64 + wv * 4 + g;
        float4 acc = hop_accum4(xp, r_lds, cnt, slots, e, g, c, nE);
        if (e < nE) yh[(size_t)e * 16 + c] = pack_half4(acc);
    }
}

// hop 3 fused with output transpose: 64-entity LDS tile, stores (B, N_E) fp32.
__global__ __launch_bounds__(HOP_TPB, 8)
void hop_out_kernel(const uint2* __restrict__ xp, const float4* __restrict__ rT4,
                    const int* __restrict__ cnt, const unsigned* __restrict__ slots,
                    float* __restrict__ out, int nE, int nR) {
    __shared__ float4 r_lds[NRMAX * RSTRIDE];
    __shared__ float tile[64][65];
    for (int i = threadIdx.x; i < nR * 16; i += HOP_TPB)
        r_lds[(i >> 4) * RSTRIDE + (i & 15)] = rT4[i];
    __syncthreads();
    int lane = threadIdx.x & 63;
    int g = lane >> 4, c = lane & 15;
    int wv = threadIdx.x >> 6;                   // 0..15
    int nTiles = (nE + 63) >> 6;
    for (int t = blockIdx.x; t < nTiles; t += gridDim.x) {
        int e0 = t * 64;
        int ei = wv * 4 + g;                     // 0..63 unique per (wv,g)
        float4 acc = hop_accum4(xp, r_lds, cnt, slots, e0 + ei, g, c, nE);
        tile[ei][4 * c + 0] = acc.x;
        tile[ei][4 * c + 1] = acc.y;
        tile[ei][4 * c + 2] = acc.z;
        tile[ei][4 * c + 3] = acc.w;
        __syncthreads();
        #pragma unroll
        for (int k = 0; k < 4; ++k) {
            int b = wv * 4 + k;
            int e = e0 + lane;
            if (e < nE) out[(size_t)b * nE + e] = tile[lane][b];
        }
        __syncthreads();                         // tile reused next iteration
    }
}

// ---- overflow merge (exercised every run on ~3 triples) ----
__device__ __forceinline__ void atom_add_h2(unsigned* addr, float a, float b) {
    unsigned old = __atomic_load_n(addr, __ATOMIC_RELAXED), assumed;
    do {
        assumed = old;
        float2 f = __half22float2(*(__half2*)&assumed);
        __half2 nh = __floats2half2_rn(f.x + a, f.y + b);
        old = atomicCAS(addr, assumed, *(unsigned*)&nh);
    } while (old != assumed);
}

// adds overflow contributions into fp16 (N_E,64) intermediate
__global__ void ovf_mid_kernel(const uint2* __restrict__ xp, const float* __restrict__ rTl,
                               const int* __restrict__ novf, const int* __restrict__ ovf_obj,
                               const unsigned* __restrict__ ovf_pk, uint2* __restrict__ yh) {
    int n = min(*novf, OVF_CAP);
    int c = threadIdx.x & 15, grp = threadIdx.x >> 4;   // 64 threads = 4 groups
    for (int i = blockIdx.x * 4 + grp; i < n; i += gridDim.x * 4) {
        int o = ovf_obj[i];
        unsigned p = ovf_pk[i];
        float4 xf = h4_to_f4(xp[(size_t)(p & 0x3FFFFu) * 16 + c]);
        const float* rr = rTl + (size_t)(p >> 18) * 64 + c * 4;
        unsigned* w = (unsigned*)&yh[(size_t)o * 16 + c];
        atom_add_h2(w,     xf.x * rr[0], xf.y * rr[1]);
        atom_add_h2(w + 1, xf.z * rr[2], xf.w * rr[3]);
    }
}

// adds overflow contributions into fp32 (B, N_E) output
__global__ void ovf_out_kernel(const uint2* __restrict__ xp, const float* __restrict__ rTl,
                               const int* __restrict__ novf, const int* __restrict__ ovf_obj,
                               const unsigned* __restrict__ ovf_pk, float* __restrict__ out, int nE) {
    int n = min(*novf, OVF_CAP);
    int c = threadIdx.x & 15, grp = threadIdx.x >> 4;
    for (int i = blockIdx.x * 4 + grp; i < n; i += gridDim.x * 4) {
        int o = ovf_obj[i];
        unsigned p = ovf_pk[i];
        float4 xf = h4_to_f4(xp[(size_t)(p & 0x3FFFFu) * 16 + c]);
        const float* rr = rTl + (size_t)(p >> 18) * 64 + c * 4;
        atomicAdd(&out[(size_t)(4 * c + 0) * nE + o], xf.x * rr[0]);
        atomicAdd(&out[(size_t)(4 * c + 1) * nE + o], xf.y * rr[1]);
        atomicAdd(&out[(size_t)(4 * c + 2) * nE + o], xf.z * rr[2]);
        atomicAdd(&out[(size_t)(4 * c + 3) * nE + o], xf.w * rr[3]);
    }
}

extern "C" void kernel_launch(void* const* d_in, const int* in_sizes, int n_in,
                              void* d_out, int out_size, void* d_ws, size_t ws_size,
                              hipStream_t stream) {
    const float* x  = (const float*)d_in[0];
    const float* q  = (const float*)d_in[1];
    const float* W1 = (const float*)d_in[2];
    const float* b1 = (const float*)d_in[3];
    const float* W2 = (const float*)d_in[4];
    const float* b2 = (const float*)d_in[5];
    const float* W3 = (const float*)d_in[6];
    const float* b3 = (const float*)d_in[7];
    const int* subj = (const int*)d_in[8];
    const int* rel  = (const int*)d_in[9];
    const int* obj  = (const int*)d_in[10];
    // n_hop (d_in[11]) is the constant 3 per the reference; hops hardcoded.

    const int B     = 64;
    const int N_E   = in_sizes[0] / B;   // 200000
    const int N_W2V = in_sizes[1] / B;   // 300
    const int N_R   = in_sizes[3];       // 200
    const int N_T   = in_sizes[8];       // 1000000

    const size_t h16bytes = (size_t)N_E * B * sizeof(__half);   // 25.6MB per fp16 buffer

    // ws layout: [cnt nE][novf 1+pad][ovf_obj][ovf_pk][slots nE*CAP][rT][X0 fp16][H1 fp16?]
    // Unconditional use ~39.6MB; R0's kernel used 57.8MB unconditionally and
    // passed, so ws_size >= that. H1 falls back to d_out scratch if tight.
    int*      cnt     = (int*)d_ws;
    int*      novf    = cnt + N_E;
    int*      ovf_obj = novf + 4;
    unsigned* ovf_pk  = (unsigned*)(ovf_obj + OVF_CAP);
    unsigned* slots   = ovf_pk + OVF_CAP;
    char*     rT_raw  = (char*)(slots + (size_t)N_E * CAP);
    float*    rT      = (float*)(((uintptr_t)rT_raw + 15) & ~(uintptr_t)15);
    char*     X0      = (char*)(rT + (size_t)3 * N_R * B);      // 16B-aligned
    size_t used = (size_t)(X0 - (char*)d_ws) + h16bytes;

    char* H1;
    if (ws_size >= used + h16bytes) {
        H1 = X0 + h16bytes;
        used += h16bytes;
    } else {
        H1 = (char*)d_out;   // 25.6MB scratch in the 51.2MB output; dead before hop3's write
    }
    char* H2 = X0;           // X0 dead after hop1

    // 1) r for all three layers
    {
        dim3 rgrid((3 * N_R + 63) / 64, B / 4);
        compute_r_kernel<<<rgrid, 256, 0, stream>>>(q, W1, b1, W2, b2, W3, b3, rT, N_R, N_W2V);
    }

    // 2) transpose x -> X0 (fp16)
    int tgrid = (N_E + 63) / 64;
    transpose_in_f16_kernel<<<tgrid, 256, 0, stream>>>(x, (__half2*)X0, N_E);

    // 3) bucket build: one XCD-sharded atomic pass (covers cnt + novf zeroing)
    hipMemsetAsync(cnt, 0, (size_t)(N_E + 4) * sizeof(int), stream);
    scatter_direct_kernel<<<CSR_BLOCKS, CSR_TPB, 0, stream>>>(
        subj, rel, obj, cnt, slots, novf, ovf_obj, ovf_pk, N_T, N_E);

    // 4) three hops (+ tiny overflow merge after each); hop3 fuses the transpose
    int nTiles  = (N_E + 63) / 64;                 // 3125
    int hblocks = nTiles < HOP_BLOCKS ? nTiles : HOP_BLOCKS;
    const float* rT1 = rT;
    const float* rT2 = rT + (size_t)1 * N_R * B;
    const float* rT3 = rT + (size_t)2 * N_R * B;

    hop_mid_kernel<<<hblocks, HOP_TPB, 0, stream>>>(
        (const uint2*)X0, (const float4*)rT1, cnt, slots, (uint2*)H1, N_E, N_R);
    ovf_mid_kernel<<<16, 64, 0, stream>>>(
        (const uint2*)X0, rT1, novf, ovf_obj, ovf_pk, (uint2*)H1);

    hop_mid_kernel<<<hblocks, HOP_TPB, 0, stream>>>(
        (const uint2*)H1, (const float4*)rT2, cnt, slots, (uint2*)H2, N_E, N_R);
    ovf_mid_kernel<<<16, 64, 0, stream>>>(
        (const uint2*)H1, rT2, novf, ovf_obj, ovf_pk, (uint2*)H2);

    hop_out_kernel<<<hblocks, HOP_TPB, 0, stream>>>(
        (const uint2*)H2, (const float4*)rT3, cnt, slots, (float*)d_out, N_E, N_R);
    ovf_out_kernel<<<16, 64, 0, stream>>>(
        (const uint2*)H2, rT3, novf, ovf_obj, ovf_pk, (float*)d_out, N_E);
}